// Round 19
// baseline (679.315 us; speedup 1.0000x reference)
//
#include <hip/hip_runtime.h>
#include <math.h>

// BS=128, L=256, D=512, H=2, DK=256.
// Conv branches dead (gather idx < 256). ALL GEMMs 1-pass bf16 MFMA, 2-phase
// __syncthreads-only. Compositions: Wa = Wfq@Wq_h, Wb = Wfk@Wk_h (both
// gate-shielded). G = (cap@Wb^T+bb)*(cap@Wa^T+ba). K never stored (fp32 in
// kg epilogue). V GEMM removed via x=(p@cap)@Wv^T+bv.
// Dispatch-count consolidation (launch overhead dominated): 5 dispatches:
// prep(cast+compose) | gemm_g+qg | gemm_kg | pbar+bnx | mlp(1+2+norm).

typedef short bf16x8 __attribute__((ext_vector_type(8)));
typedef float f32x4 __attribute__((ext_vector_type(4)));
typedef short short4v __attribute__((ext_vector_type(4)));

__device__ __forceinline__ short f2bf(float x) {
    union { float f; unsigned u; } c; c.f = x;
    unsigned r = c.u + 0x7FFFu + ((c.u >> 16) & 1u);
    return (short)(r >> 16);
}
__device__ __forceinline__ float bf2f(short h) {
    union { float f; unsigned u; } c; c.u = ((unsigned)(unsigned short)h) << 16;
    return c.f;
}
__device__ __forceinline__ void glds16(const void* g, void* l) {
    __builtin_amdgcn_global_load_lds(
        (const __attribute__((address_space(1))) void*)g,
        (__attribute__((address_space(3))) void*)l, 16, 0, 0);
}

// ---------------- prep: bf16 casts + composed weights, one dispatch ----------------
struct PrepArgs {
    const float* src[3];
    short* dst[3];
    int n4[3];
    const float *Wq, *bq, *Wfq, *bfq, *Wk, *bk, *Wfk, *bfk;
    short *WaB, *WbB;
    float *ba, *bb;
};
__global__ __launch_bounds__(256) void prep_kernel(PrepArgs a)
{
    const int y = blockIdx.y;
    const int t = threadIdx.x;
    if (y < 3) {
        const float4* s = (const float4*)a.src[y];
        short* d = a.dst[y];
        const int n4 = a.n4[y];
        for (int i = blockIdx.x * 256 + t; i < n4; i += gridDim.x * 256) {
            float4 x = s[i];
            short4v h;
            h.x = f2bf(x.x); h.y = f2bf(x.y); h.z = f2bf(x.z); h.w = f2bf(x.w);
            *(short4v*)&d[i * 4] = h;
        }
        return;
    }
    if (blockIdx.x >= 512) return;
    __shared__ float fq[256];
    __shared__ float redc[256];
    const int op = blockIdx.x;
    const int h = op >> 8, o = op & 255;
    const bool second = (y == 4);
    const float* W  = second ? a.Wk  : a.Wq;
    const float* bv = second ? a.bk  : a.bq;
    const float* F  = second ? a.Wfk : a.Wfq;
    const float* bf = second ? a.bfk : a.bfq;
    short* WB   = second ? a.WbB : a.WaB;
    float* bout = second ? a.bb  : a.ba;

    fq[t] = F[o * 256 + t];
    redc[t] = fq[t] * bv[h * 256 + t];
    __syncthreads();
    for (int s = 128; s > 0; s >>= 1) {
        if (t < s) redc[t] += redc[t + s];
        __syncthreads();
    }
    if (t == 0) bout[op] = redc[0] + bf[o];
    float s0 = 0.f, s1 = 0.f;
    for (int d = 0; d < 256; ++d) {
        const float f = fq[d];
        const float* wr = W + (size_t)(h * 256 + d) * 512;
        s0 += f * wr[t];
        s1 += f * wr[t + 256];
    }
    const size_t ro = (size_t)op * 512;
    WB[ro + t] = f2bf(s0);
    WB[ro + 256 + t] = f2bf(s1);
}

// ---------------- gemm_g (1024 blocks) + qg (256 blocks, self-contained) ----------------
__global__ __launch_bounds__(256)
void gemm_g_qg(const short* __restrict__ capB,
               const short* __restrict__ WaB, const short* __restrict__ WbB,
               const float* __restrict__ ba, const float* __restrict__ bb,
               short* __restrict__ Gbuf,
               const float* __restrict__ cap,
               const float* __restrict__ Wq, const float* __restrict__ bq,
               const float* __restrict__ Wfg, const float* __restrict__ bfg,
               const int* __restrict__ lengths, float* __restrict__ qg)
{
    __shared__ short lds[2][12288];
    const int tid = threadIdx.x;

    if (blockIdx.x < 256) {
        // ---- qg path: computes its own G at the gathered row (validated r17) ----
        float* cr = (float*)&lds[0][0];     // 512 floats
        float* gs = cr + 512;               // 256 floats
        const int b = blockIdx.x >> 1, h = blockIdx.x & 1;
        const int t = tid;
        int r = lengths[b] - 1;
        if (r < 0) r = 0;
        if (r > 255) r = 255;
        const size_t base = ((size_t)b * 256 + r) * 512;
        cr[t] = cap[base + t];
        cr[t + 256] = cap[base + 256 + t];
        __syncthreads();
        {
            const bf16x8* wa8 = (const bf16x8*)(WaB + (size_t)(h * 256 + t) * 512);
            const bf16x8* wb8 = (const bf16x8*)(WbB + (size_t)(h * 256 + t) * 512);
            float sa = 0.f, sb = 0.f;
            for (int k8 = 0; k8 < 64; ++k8) {
                bf16x8 wa = wa8[k8];
                bf16x8 wb = wb8[k8];
#pragma unroll
                for (int j = 0; j < 8; ++j) {
                    const float c = cr[k8 * 8 + j];
                    sa += bf2f(wa[j]) * c;
                    sb += bf2f(wb[j]) * c;
                }
            }
            gs[t] = (sb + bb[h * 256 + t]) * (sa + ba[h * 256 + t]);
        }
        __syncthreads();
        const float4* wq4 = (const float4*)(Wq + (size_t)(h * 256 + t) * 512);
        float q = 0.f;
        for (int k4 = 0; k4 < 128; ++k4) {
            float4 w = wq4[k4];
            q += w.x * cr[k4 * 4 + 0] + w.y * cr[k4 * 4 + 1]
               + w.z * cr[k4 * 4 + 2] + w.w * cr[k4 * 4 + 3];
        }
        q += bq[h * 256 + t];
        const float4* w4 = (const float4*)(Wfg + (size_t)t * 256);
        float a = 0.f;
        for (int k4 = 0; k4 < 64; ++k4) {
            float4 w = w4[k4];
            a += w.x * gs[k4 * 4 + 0] + w.y * gs[k4 * 4 + 1]
               + w.z * gs[k4 * 4 + 2] + w.w * gs[k4 * 4 + 3];
        }
        a += bfg[t];
        qg[b * 512 + h * 256 + t] = q / (1.f + expf(-a));
        return;
    }

    // ---- gemm_g path ----
    const int gid = blockIdx.x - 256;
    const int bn = (gid & 1) * 128;
    const int bm = ((gid >> 1) & 255) * 128;
    const int z = gid >> 9;
    const short* B1 = WaB + (size_t)z * 256 * 512;
    const short* B2 = WbB + (size_t)z * 256 * 512;

    const int lane = tid & 63;
    const int wr = (tid >> 7) & 1, wc = (tid >> 6) & 1;
    const int fr = lane & 15, kc = lane >> 4;
    const int r0 = tid >> 2;
    const int e0 = (((tid & 3) ^ ((r0 >> 1) & 3))) * 8;
    const int kce = (kc ^ ((fr >> 1) & 3)) * 8;

    auto stage = [&](int ph, int k0) {
        short* b = lds[ph];
        glds16(capB + (size_t)(bm + r0) * 512 + k0 + e0,      b + tid * 8);
        glds16(capB + (size_t)(bm + r0 + 64) * 512 + k0 + e0, b + (tid + 256) * 8);
        glds16(B1 + (size_t)(bn + r0) * 512 + k0 + e0,        b + 4096 + tid * 8);
        glds16(B1 + (size_t)(bn + r0 + 64) * 512 + k0 + e0,   b + 4096 + (tid + 256) * 8);
        glds16(B2 + (size_t)(bn + r0) * 512 + k0 + e0,        b + 8192 + tid * 8);
        glds16(B2 + (size_t)(bn + r0 + 64) * 512 + k0 + e0,   b + 8192 + (tid + 256) * 8);
    };

    f32x4 acc1[4][4], acc2[4][4];
#pragma unroll
    for (int i = 0; i < 4; ++i)
#pragma unroll
        for (int j = 0; j < 4; ++j) {
            acc1[i][j] = (f32x4){0.f, 0.f, 0.f, 0.f};
            acc2[i][j] = (f32x4){0.f, 0.f, 0.f, 0.f};
        }

    stage(0, 0);
    __syncthreads();
    for (int s = 0; s < 16; ++s) {
        if (s + 1 < 16) stage((s + 1) & 1, (s + 1) * 32);
        const short* b = lds[s & 1];
        bf16x8 ah[4], bh[4];
#pragma unroll
        for (int i = 0; i < 4; ++i)
            ah[i] = *(const bf16x8*)&b[(wr * 64 + i * 16 + fr) * 32 + kce];
#pragma unroll
        for (int i = 0; i < 4; ++i)
            bh[i] = *(const bf16x8*)&b[4096 + (wc * 64 + i * 16 + fr) * 32 + kce];
#pragma unroll
        for (int mi = 0; mi < 4; ++mi)
#pragma unroll
            for (int ni = 0; ni < 4; ++ni)
                acc1[mi][ni] = __builtin_amdgcn_mfma_f32_16x16x32_bf16(ah[mi], bh[ni], acc1[mi][ni], 0, 0, 0);
#pragma unroll
        for (int i = 0; i < 4; ++i)
            bh[i] = *(const bf16x8*)&b[8192 + (wc * 64 + i * 16 + fr) * 32 + kce];
#pragma unroll
        for (int mi = 0; mi < 4; ++mi)
#pragma unroll
            for (int ni = 0; ni < 4; ++ni)
                acc2[mi][ni] = __builtin_amdgcn_mfma_f32_16x16x32_bf16(ah[mi], bh[ni], acc2[mi][ni], 0, 0, 0);
        __syncthreads();
    }

#pragma unroll
    for (int mi = 0; mi < 4; ++mi) {
#pragma unroll
        for (int ni = 0; ni < 4; ++ni) {
#pragma unroll
            for (int r = 0; r < 4; ++r) {
                const int row = bm + wr * 64 + mi * 16 + kc * 4 + r;
                const int col = bn + wc * 64 + ni * 16 + fr;
                const float av  = acc1[mi][ni][r] + ba[z * 256 + col];
                const float lin = acc2[mi][ni][r] + bb[z * 256 + col];
                Gbuf[(size_t)row * 512 + z * 256 + col] = f2bf(lin * av);
            }
        }
    }
}

// ---------------- kg: interleaved dual kloop + fused score partials ----------------
__global__ __launch_bounds__(256, 2)
void gemm_kg(const short* __restrict__ Gbuf,
             const short* __restrict__ Wfg2B, const float* __restrict__ bias,
             const short* __restrict__ capB,
             const short* __restrict__ WkB, const float* __restrict__ bk,
             const float* __restrict__ qg, float* __restrict__ scorep)
{
    __shared__ short lds[2][16384];
    __shared__ float sp[256];
    const int tid = threadIdx.x;
    const int bm = blockIdx.y * 128;
    const int bn = blockIdx.x * 128;
    const int z = blockIdx.z;
    const short* A1 = Gbuf + (size_t)z * 256;
    const short* B2 = WkB + (size_t)z * 256 * 512;

    const int lane = tid & 63;
    const int wr = (tid >> 7) & 1, wc = (tid >> 6) & 1;
    const int fr = lane & 15, kc = lane >> 4;
    const int r0 = tid >> 2;
    const int e0 = (((tid & 3) ^ ((r0 >> 1) & 3))) * 8;
    const int kce = (kc ^ ((fr >> 1) & 3)) * 8;

    auto stage = [&](int ph, int s) {
        short* b = lds[ph];
        const int k0 = s * 32;
        glds16(capB + (size_t)(bm + r0) * 512 + k0 + e0,      b + 8192 + tid * 8);
        glds16(capB + (size_t)(bm + r0 + 64) * 512 + k0 + e0, b + 8192 + (tid + 256) * 8);
        glds16(B2 + (size_t)(bn + r0) * 512 + k0 + e0,        b + 12288 + tid * 8);
        glds16(B2 + (size_t)(bn + r0 + 64) * 512 + k0 + e0,   b + 12288 + (tid + 256) * 8);
        if (s < 8) {
            glds16(A1 + (size_t)(bm + r0) * 512 + k0 + e0,        b + tid * 8);
            glds16(A1 + (size_t)(bm + r0 + 64) * 512 + k0 + e0,   b + (tid + 256) * 8);
            glds16(Wfg2B + (size_t)(bn + r0) * 256 + k0 + e0,     b + 4096 + tid * 8);
            glds16(Wfg2B + (size_t)(bn + r0 + 64) * 256 + k0 + e0, b + 4096 + (tid + 256) * 8);
        }
    };

    f32x4 acc1[4][4], acc2[4][4];
#pragma unroll
    for (int i = 0; i < 4; ++i)
#pragma unroll
        for (int j = 0; j < 4; ++j) {
            acc1[i][j] = (f32x4){0.f, 0.f, 0.f, 0.f};
            acc2[i][j] = (f32x4){0.f, 0.f, 0.f, 0.f};
        }

    stage(0, 0);
    __syncthreads();
    for (int s = 0; s < 16; ++s) {
        if (s + 1 < 16) stage((s + 1) & 1, s + 1);
        const short* b = lds[s & 1];
        bf16x8 ah[4], bh[4];
#pragma unroll
        for (int i = 0; i < 4; ++i)
            ah[i] = *(const bf16x8*)&b[8192 + (wr * 64 + i * 16 + fr) * 32 + kce];
#pragma unroll
        for (int i = 0; i < 4; ++i)
            bh[i] = *(const bf16x8*)&b[12288 + (wc * 64 + i * 16 + fr) * 32 + kce];
#pragma unroll
        for (int mi = 0; mi < 4; ++mi)
#pragma unroll
            for (int ni = 0; ni < 4; ++ni)
                acc2[mi][ni] = __builtin_amdgcn_mfma_f32_16x16x32_bf16(ah[mi], bh[ni], acc2[mi][ni], 0, 0, 0);
        if (s < 8) {
#pragma unroll
            for (int i = 0; i < 4; ++i)
                ah[i] = *(const bf16x8*)&b[(wr * 64 + i * 16 + fr) * 32 + kce];
#pragma unroll
            for (int i = 0; i < 4; ++i)
                bh[i] = *(const bf16x8*)&b[4096 + (wc * 64 + i * 16 + fr) * 32 + kce];
#pragma unroll
            for (int mi = 0; mi < 4; ++mi)
#pragma unroll
                for (int ni = 0; ni < 4; ++ni)
                    acc1[mi][ni] = __builtin_amdgcn_mfma_f32_16x16x32_bf16(ah[mi], bh[ni], acc1[mi][ni], 0, 0, 0);
        }
        __syncthreads();
    }

    float qgv[4];
    float pt[4][4];
    {
        const int b = bm >> 8;
#pragma unroll
        for (int ni = 0; ni < 4; ++ni)
            qgv[ni] = qg[b * 512 + z * 256 + bn + wc * 64 + ni * 16 + fr];
#pragma unroll
        for (int mi = 0; mi < 4; ++mi)
#pragma unroll
            for (int r = 0; r < 4; ++r) pt[mi][r] = 0.f;
    }

#pragma unroll
    for (int mi = 0; mi < 4; ++mi) {
#pragma unroll
        for (int ni = 0; ni < 4; ++ni) {
#pragma unroll
            for (int r = 0; r < 4; ++r) {
                const int col = bn + wc * 64 + ni * 16 + fr;
                const float v = acc1[mi][ni][r] + bias[col];
                const float e = acc2[mi][ni][r] + bk[z * 256 + col];
                const float kgv = e / (1.f + expf(-v));
                pt[mi][r] += kgv * qgv[ni];
            }
        }
    }

#pragma unroll
    for (int mi = 0; mi < 4; ++mi) {
#pragma unroll
        for (int r = 0; r < 4; ++r) {
            float p = pt[mi][r];
            p += __shfl_xor(p, 1);
            p += __shfl_xor(p, 2);
            p += __shfl_xor(p, 4);
            p += __shfl_xor(p, 8);
            if (fr == 0) {
                const int row_local = wr * 64 + mi * 16 + kc * 4 + r;
                sp[row_local * 2 + wc] = p;
            }
        }
    }
    __syncthreads();
    if (tid < 128) {
        const int row = bm + tid;
        const float s = sp[tid * 2] + sp[tid * 2 + 1];
        const int b = row >> 8, j = row & 255;
        scorep[((size_t)(b * 2 + z) * 256 + j) * 2 + blockIdx.x] = s;
    }
}

// ---------------- fused softmax + pbar (LDS) + BN1/residual ----------------
__global__ __launch_bounds__(256)
void pbar_bnx(const float* __restrict__ scorep, const short* __restrict__ capB,
              const float* __restrict__ cap, const int* __restrict__ lengths,
              const float* __restrict__ Wv, const float* __restrict__ bv,
              const float* __restrict__ g1, const float* __restrict__ b1,
              const float* __restrict__ m1, const float* __restrict__ v1,
              float* __restrict__ xga)
{
    __shared__ float sc[512], red[512], pb[1024];
    const int b = blockIdx.x;
    const int t = threadIdx.x;
#pragma unroll
    for (int i = 0; i < 2; ++i) {
        const int o = t + i * 256;
        const int h = o >> 8, j = o & 255;
        const size_t si = ((size_t)(b * 2 + h) * 256 + j) * 2;
        sc[o] = floorf((scorep[si] + scorep[si + 1]) * 0.0625f);
    }
    __syncthreads();
    red[t] = sc[t]; red[t + 256] = sc[t + 256];
    __syncthreads();
    for (int s = 128; s > 0; s >>= 1) {
        if (t < s) {
            red[t] = fmaxf(red[t], red[t + s]);
            red[256 + t] = fmaxf(red[256 + t], red[256 + t + s]);
        }
        __syncthreads();
    }
    const float mx0 = red[0], mx1 = red[256];
    __syncthreads();
    const float e0 = expf(sc[t] - mx0);
    const float e1 = expf(sc[t + 256] - mx1);
    red[t] = e0; red[t + 256] = e1;
    __syncthreads();
    for (int s = 128; s > 0; s >>= 1) {
        if (t < s) { red[t] += red[t + s]; red[256 + t] += red[256 + t + s]; }
        __syncthreads();
    }
    sc[t] = e0 / red[0];
    sc[t + 256] = e1 / red[256];
    __syncthreads();

    // pbar full-width: thread t covers c = t and t+256, both heads
    float a00 = 0.f, a01 = 0.f, a10 = 0.f, a11 = 0.f;
    for (int j = 0; j < 256; ++j) {
        const float p0 = sc[j], p1 = sc[256 + j];
        const float cv0 = bf2f(capB[((size_t)(b * 256 + j)) * 512 + t]);
        const float cv1 = bf2f(capB[((size_t)(b * 256 + j)) * 512 + 256 + t]);
        a00 += p0 * cv0; a01 += p0 * cv1;
        a10 += p1 * cv0; a11 += p1 * cv1;
    }
    pb[t] = a00; pb[256 + t] = a01;
    pb[512 + t] = a10; pb[768 + t] = a11;
    __syncthreads();

    // bnx
    int r = lengths[b] - 1;
    if (r < 0) r = 0;
    if (r > 255) r = 255;
    const size_t base = ((size_t)b * 256 + r) * 512;
    float x0 = 0.f, x1 = 0.f;
    {
        const float4* w4 = (const float4*)(Wv + (size_t)t * 512);
        for (int k4 = 0; k4 < 128; ++k4) {
            float4 w = w4[k4];
            x0 += w.x * pb[k4 * 4 + 0] + w.y * pb[k4 * 4 + 1]
                + w.z * pb[k4 * 4 + 2] + w.w * pb[k4 * 4 + 3];
        }
        x0 += bv[t];
    }
    {
        const float4* w4 = (const float4*)(Wv + (size_t)(t + 256) * 512);
        for (int k4 = 0; k4 < 128; ++k4) {
            float4 w = w4[k4];
            x1 += w.x * pb[512 + k4 * 4 + 0] + w.y * pb[512 + k4 * 4 + 1]
                + w.z * pb[512 + k4 * 4 + 2] + w.w * pb[512 + k4 * 4 + 3];
        }
        x1 += bv[t + 256];
    }
    const int c0 = t, c1 = t + 256;
    const float s0 = g1[c0] / sqrtf(v1[c0] + 1e-5f);
    const float s1 = g1[c1] / sqrtf(v1[c1] + 1e-5f);
    xga[b * 512 + c0] = cap[base + c0] + (x0 - m1[c0]) * s0 + b1[c0];
    xga[b * 512 + c1] = cap[base + c1] + (x1 - m1[c1]) * s1 + b1[c1];
}

// ---------------- fused MLP: hid+tex in LDS, norm inline; 4 rows/block ----------------
__global__ __launch_bounds__(256)
void mlp_fused(const float* __restrict__ xga,
               const float* __restrict__ Wm1, const float* __restrict__ bm1,
               const float* __restrict__ Wm2, const float* __restrict__ bm2,
               float* __restrict__ out)
{
    __shared__ float xs[4 * 512];    // 8KB
    __shared__ float hs[4 * 1024];   // 16KB
    __shared__ float tx[4 * 512];    // 8KB
    __shared__ float red[256];
    const int r0 = blockIdx.x * 4;
    const int t = threadIdx.x;

#pragma unroll
    for (int i = 0; i < 8; ++i)
        xs[t + i * 256] = xga[(size_t)r0 * 512 + t + i * 256];
    __syncthreads();

    // hid = relu(xs @ Wm1^T + bm1)
#pragma unroll
    for (int i = 0; i < 16; ++i) {
        const int idx = t + i * 256;
        const int r = idx >> 10, col = idx & 1023;
        const float4* w4 = (const float4*)(Wm1 + (size_t)col * 512);
        const float* xr = xs + r * 512;
        float acc = 0.f;
        for (int k4 = 0; k4 < 128; ++k4) {
            float4 w = w4[k4];
            acc += w.x * xr[k4 * 4 + 0] + w.y * xr[k4 * 4 + 1]
                 + w.z * xr[k4 * 4 + 2] + w.w * xr[k4 * 4 + 3];
        }
        hs[idx] = fmaxf(acc + bm1[col], 0.f);
    }
    __syncthreads();

    // tex = hs @ Wm2^T + bm2 + xs
#pragma unroll
    for (int i = 0; i < 8; ++i) {
        const int idx = t + i * 256;
        const int r = idx >> 9, col = idx & 511;
        const float4* w4 = (const float4*)(Wm2 + (size_t)col * 1024);
        const float* hr = hs + r * 1024;
        float acc = 0.f;
        for (int k4 = 0; k4 < 256; ++k4) {
            float4 w = w4[k4];
            acc += w.x * hr[k4 * 4 + 0] + w.y * hr[k4 * 4 + 1]
                 + w.z * hr[k4 * 4 + 2] + w.w * hr[k4 * 4 + 3];
        }
        tx[idx] = acc + bm2[col] + xs[r * 512 + col];
    }
    __syncthreads();

    // per-row l2 norm + write
    for (int r = 0; r < 4; ++r) {
        const float v0 = tx[r * 512 + t];
        const float v1 = tx[r * 512 + 256 + t];
        red[t] = v0 * v0 + v1 * v1;
        __syncthreads();
        for (int s = 128; s > 0; s >>= 1) {
            if (t < s) red[t] += red[t + s];
            __syncthreads();
        }
        const float inv = 1.f / (sqrtf(red[0]) + 1e-8f);
        out[(size_t)(r0 + r) * 512 + t] = v0 * inv;
        out[(size_t)(r0 + r) * 512 + 256 + t] = v1 * inv;
        __syncthreads();
    }
}

extern "C" void kernel_launch(void* const* d_in, const int* in_sizes, int n_in,
                              void* d_out, int out_size, void* d_ws, size_t ws_size,
                              hipStream_t stream)
{
    const float* cap = (const float*)d_in[0];
    const int* lengths = (const int*)d_in[1];
    const float* Wq  = (const float*)d_in[2];
    const float* Wk  = (const float*)d_in[3];
    const float* Wv  = (const float*)d_in[4];
    const float* bq  = (const float*)d_in[5];
    const float* bk  = (const float*)d_in[6];
    const float* bv  = (const float*)d_in[7];
    const float* Wfq = (const float*)d_in[8];
    const float* bfq = (const float*)d_in[9];
    const float* Wfk = (const float*)d_in[10];
    const float* bfk = (const float*)d_in[11];
    const float* Wfg = (const float*)d_in[12];
    const float* bfg = (const float*)d_in[13];
    const float* g1  = (const float*)d_in[14];
    const float* b1  = (const float*)d_in[15];
    const float* m1  = (const float*)d_in[16];
    const float* v1  = (const float*)d_in[17];
    const float* Wm1 = (const float*)d_in[30];
    const float* bm1 = (const float*)d_in[31];
    const float* Wm2 = (const float*)d_in[32];
    const float* bm2 = (const float*)d_in[33];
    float* out = (float*)d_out;

    char* w = (char*)d_ws;
    const size_t MB = 1024 * 1024;
    short* capB = (short*)(w);                 // 32MB bf16 cap
    short* Gbuf = (short*)(w + 32 * MB);       // 32MB [32768,512] bf16
    char* wp = w + 64 * MB;
    short* WkB   = (short*)wp; wp += 524288;
    short* WaB   = (short*)wp; wp += 524288;
    short* WbB   = (short*)wp; wp += 524288;
    short* Wfg2B = (short*)wp; wp += 131072;
    float* ba     = (float*)wp; wp += 2048;
    float* bb     = (float*)wp; wp += 2048;
    float* qg     = (float*)wp; wp += 262144;
    float* scorep = (float*)wp; wp += 524288;   // [128][2][256][2]
    float* xga    = (float*)wp; wp += 262144;

    // 1. prep: casts + composed weights
    PrepArgs pa;
    pa.src[0] = cap;          pa.dst[0] = capB;  pa.n4[0] = 4194304;
    pa.src[1] = Wk;           pa.dst[1] = WkB;   pa.n4[1] = 65536;
    pa.src[2] = Wfg + 65536;  pa.dst[2] = Wfg2B; pa.n4[2] = 16384;
    pa.Wq = Wq; pa.bq = bq; pa.Wfq = Wfq; pa.bfq = bfq;
    pa.Wk = Wk; pa.bk = bk; pa.Wfk = Wfk; pa.bfk = bfk;
    pa.WaB = WaB; pa.WbB = WbB; pa.ba = ba; pa.bb = bb;
    prep_kernel<<<dim3(4096, 5), 256, 0, stream>>>(pa);

    // 2. gemm_g (1024 blocks) + qg (256 blocks)
    gemm_g_qg<<<dim3(1280), 256, 0, stream>>>(capB, WaB, WbB, ba, bb, Gbuf,
                                              cap, Wq, bq, Wfg, bfg, lengths, qg);

    // 3. kg gemm (interleaved dual kloop) + in-kernel K (fp32) + fused scores
    gemm_kg<<<dim3(2, 256, 2), 256, 0, stream>>>(Gbuf, Wfg2B, bfg + 256,
                                                 capB, WkB, bk, qg, scorep);

    // 4. softmax + pbar + BN/residual
    pbar_bnx<<<dim3(128), 256, 0, stream>>>(scorep, capB, cap, lengths,
                                            Wv, bv, g1, b1, m1, v1, xga);

    // 5. fused MLP + norm
    mlp_fused<<<dim3(32), 256, 0, stream>>>(xga, Wm1, bm1, Wm2, bm2, out);
}

// Round 20
// 295.237 us; speedup vs baseline: 2.3009x; 2.3009x over previous
//
#include <hip/hip_runtime.h>
#include <math.h>

// BS=128, L=256, D=512, H=2, DK=256.
// Conv branches dead (gather idx < 256). ALL GEMMs 1-pass bf16 MFMA, 2-phase
// __syncthreads-only. Compositions: Wa = Wfq@Wq_h, Wb = Wfk@Wk_h (both
// gate-shielded). G = (cap@Wb^T+bb)*(cap@Wa^T+ba). K never stored (fp32 in
// kg epilogue). V GEMM removed via x=(p@cap)@Wv^T+bv.
// 7 dispatches: prep | gemm_g+qg | gemm_kg | pbar+bnx | mlp1 | mlp2 | norm.
// (r19 lesson: mlp_fused at 32 blocks was 456us — occupancy catastrophe;
// strip-GEMM tail restored.)

typedef short bf16x8 __attribute__((ext_vector_type(8)));
typedef float f32x4 __attribute__((ext_vector_type(4)));
typedef short short4v __attribute__((ext_vector_type(4)));

__device__ __forceinline__ short f2bf(float x) {
    union { float f; unsigned u; } c; c.f = x;
    unsigned r = c.u + 0x7FFFu + ((c.u >> 16) & 1u);
    return (short)(r >> 16);
}
__device__ __forceinline__ float bf2f(short h) {
    union { float f; unsigned u; } c; c.u = ((unsigned)(unsigned short)h) << 16;
    return c.f;
}
__device__ __forceinline__ void glds16(const void* g, void* l) {
    __builtin_amdgcn_global_load_lds(
        (const __attribute__((address_space(1))) void*)g,
        (__attribute__((address_space(3))) void*)l, 16, 0, 0);
}

// ---------------- prep: bf16 casts + composed weights, one dispatch ----------------
struct PrepArgs {
    const float* src[3];
    short* dst[3];
    int n4[3];
    const float *Wq, *bq, *Wfq, *bfq, *Wk, *bk, *Wfk, *bfk;
    short *WaB, *WbB;
    float *ba, *bb;
};
__global__ __launch_bounds__(256) void prep_kernel(PrepArgs a)
{
    const int y = blockIdx.y;
    const int t = threadIdx.x;
    if (y < 3) {
        const float4* s = (const float4*)a.src[y];
        short* d = a.dst[y];
        const int n4 = a.n4[y];
        for (int i = blockIdx.x * 256 + t; i < n4; i += gridDim.x * 256) {
            float4 x = s[i];
            short4v h;
            h.x = f2bf(x.x); h.y = f2bf(x.y); h.z = f2bf(x.z); h.w = f2bf(x.w);
            *(short4v*)&d[i * 4] = h;
        }
        return;
    }
    if (blockIdx.x >= 512) return;
    __shared__ float fq[256];
    __shared__ float redc[256];
    const int op = blockIdx.x;
    const int h = op >> 8, o = op & 255;
    const bool second = (y == 4);
    const float* W  = second ? a.Wk  : a.Wq;
    const float* bv = second ? a.bk  : a.bq;
    const float* F  = second ? a.Wfk : a.Wfq;
    const float* bf = second ? a.bfk : a.bfq;
    short* WB   = second ? a.WbB : a.WaB;
    float* bout = second ? a.bb  : a.ba;

    fq[t] = F[o * 256 + t];
    redc[t] = fq[t] * bv[h * 256 + t];
    __syncthreads();
    for (int s = 128; s > 0; s >>= 1) {
        if (t < s) redc[t] += redc[t + s];
        __syncthreads();
    }
    if (t == 0) bout[op] = redc[0] + bf[o];
    float s0 = 0.f, s1 = 0.f;
    for (int d = 0; d < 256; ++d) {
        const float f = fq[d];
        const float* wr = W + (size_t)(h * 256 + d) * 512;
        s0 += f * wr[t];
        s1 += f * wr[t + 256];
    }
    const size_t ro = (size_t)op * 512;
    WB[ro + t] = f2bf(s0);
    WB[ro + 256 + t] = f2bf(s1);
}

// ---------------- gemm_g (1024 blocks) + qg (256 blocks, self-contained) ----------------
__global__ __launch_bounds__(256)
void gemm_g_qg(const short* __restrict__ capB,
               const short* __restrict__ WaB, const short* __restrict__ WbB,
               const float* __restrict__ ba, const float* __restrict__ bb,
               short* __restrict__ Gbuf,
               const float* __restrict__ cap,
               const float* __restrict__ Wq, const float* __restrict__ bq,
               const float* __restrict__ Wfg, const float* __restrict__ bfg,
               const int* __restrict__ lengths, float* __restrict__ qg)
{
    __shared__ short lds[2][12288];
    const int tid = threadIdx.x;

    if (blockIdx.x < 256) {
        // ---- qg path: computes its own G at the gathered row ----
        float* cr = (float*)&lds[0][0];     // 512 floats
        float* gs = cr + 512;               // 256 floats
        const int b = blockIdx.x >> 1, h = blockIdx.x & 1;
        const int t = tid;
        int r = lengths[b] - 1;
        if (r < 0) r = 0;
        if (r > 255) r = 255;
        const size_t base = ((size_t)b * 256 + r) * 512;
        cr[t] = cap[base + t];
        cr[t + 256] = cap[base + 256 + t];
        __syncthreads();
        {
            const bf16x8* wa8 = (const bf16x8*)(WaB + (size_t)(h * 256 + t) * 512);
            const bf16x8* wb8 = (const bf16x8*)(WbB + (size_t)(h * 256 + t) * 512);
            float sa = 0.f, sb = 0.f;
            for (int k8 = 0; k8 < 64; ++k8) {
                bf16x8 wa = wa8[k8];
                bf16x8 wb = wb8[k8];
#pragma unroll
                for (int j = 0; j < 8; ++j) {
                    const float c = cr[k8 * 8 + j];
                    sa += bf2f(wa[j]) * c;
                    sb += bf2f(wb[j]) * c;
                }
            }
            gs[t] = (sb + bb[h * 256 + t]) * (sa + ba[h * 256 + t]);
        }
        __syncthreads();
        const float4* wq4 = (const float4*)(Wq + (size_t)(h * 256 + t) * 512);
        float q = 0.f;
        for (int k4 = 0; k4 < 128; ++k4) {
            float4 w = wq4[k4];
            q += w.x * cr[k4 * 4 + 0] + w.y * cr[k4 * 4 + 1]
               + w.z * cr[k4 * 4 + 2] + w.w * cr[k4 * 4 + 3];
        }
        q += bq[h * 256 + t];
        const float4* w4 = (const float4*)(Wfg + (size_t)t * 256);
        float a = 0.f;
        for (int k4 = 0; k4 < 64; ++k4) {
            float4 w = w4[k4];
            a += w.x * gs[k4 * 4 + 0] + w.y * gs[k4 * 4 + 1]
               + w.z * gs[k4 * 4 + 2] + w.w * gs[k4 * 4 + 3];
        }
        a += bfg[t];
        qg[b * 512 + h * 256 + t] = q / (1.f + expf(-a));
        return;
    }

    // ---- gemm_g path ----
    const int gid = blockIdx.x - 256;
    const int bn = (gid & 1) * 128;
    const int bm = ((gid >> 1) & 255) * 128;
    const int z = gid >> 9;
    const short* B1 = WaB + (size_t)z * 256 * 512;
    const short* B2 = WbB + (size_t)z * 256 * 512;

    const int lane = tid & 63;
    const int wr = (tid >> 7) & 1, wc = (tid >> 6) & 1;
    const int fr = lane & 15, kc = lane >> 4;
    const int r0 = tid >> 2;
    const int e0 = (((tid & 3) ^ ((r0 >> 1) & 3))) * 8;
    const int kce = (kc ^ ((fr >> 1) & 3)) * 8;

    auto stage = [&](int ph, int k0) {
        short* b = lds[ph];
        glds16(capB + (size_t)(bm + r0) * 512 + k0 + e0,      b + tid * 8);
        glds16(capB + (size_t)(bm + r0 + 64) * 512 + k0 + e0, b + (tid + 256) * 8);
        glds16(B1 + (size_t)(bn + r0) * 512 + k0 + e0,        b + 4096 + tid * 8);
        glds16(B1 + (size_t)(bn + r0 + 64) * 512 + k0 + e0,   b + 4096 + (tid + 256) * 8);
        glds16(B2 + (size_t)(bn + r0) * 512 + k0 + e0,        b + 8192 + tid * 8);
        glds16(B2 + (size_t)(bn + r0 + 64) * 512 + k0 + e0,   b + 8192 + (tid + 256) * 8);
    };

    f32x4 acc1[4][4], acc2[4][4];
#pragma unroll
    for (int i = 0; i < 4; ++i)
#pragma unroll
        for (int j = 0; j < 4; ++j) {
            acc1[i][j] = (f32x4){0.f, 0.f, 0.f, 0.f};
            acc2[i][j] = (f32x4){0.f, 0.f, 0.f, 0.f};
        }

    stage(0, 0);
    __syncthreads();
    for (int s = 0; s < 16; ++s) {
        if (s + 1 < 16) stage((s + 1) & 1, (s + 1) * 32);
        const short* b = lds[s & 1];
        bf16x8 ah[4], bh[4];
#pragma unroll
        for (int i = 0; i < 4; ++i)
            ah[i] = *(const bf16x8*)&b[(wr * 64 + i * 16 + fr) * 32 + kce];
#pragma unroll
        for (int i = 0; i < 4; ++i)
            bh[i] = *(const bf16x8*)&b[4096 + (wc * 64 + i * 16 + fr) * 32 + kce];
#pragma unroll
        for (int mi = 0; mi < 4; ++mi)
#pragma unroll
            for (int ni = 0; ni < 4; ++ni)
                acc1[mi][ni] = __builtin_amdgcn_mfma_f32_16x16x32_bf16(ah[mi], bh[ni], acc1[mi][ni], 0, 0, 0);
#pragma unroll
        for (int i = 0; i < 4; ++i)
            bh[i] = *(const bf16x8*)&b[8192 + (wc * 64 + i * 16 + fr) * 32 + kce];
#pragma unroll
        for (int mi = 0; mi < 4; ++mi)
#pragma unroll
            for (int ni = 0; ni < 4; ++ni)
                acc2[mi][ni] = __builtin_amdgcn_mfma_f32_16x16x32_bf16(ah[mi], bh[ni], acc2[mi][ni], 0, 0, 0);
        __syncthreads();
    }

#pragma unroll
    for (int mi = 0; mi < 4; ++mi) {
#pragma unroll
        for (int ni = 0; ni < 4; ++ni) {
#pragma unroll
            for (int r = 0; r < 4; ++r) {
                const int row = bm + wr * 64 + mi * 16 + kc * 4 + r;
                const int col = bn + wc * 64 + ni * 16 + fr;
                const float av  = acc1[mi][ni][r] + ba[z * 256 + col];
                const float lin = acc2[mi][ni][r] + bb[z * 256 + col];
                Gbuf[(size_t)row * 512 + z * 256 + col] = f2bf(lin * av);
            }
        }
    }
}

// ---------------- kg: interleaved dual kloop + fused score partials ----------------
__global__ __launch_bounds__(256, 2)
void gemm_kg(const short* __restrict__ Gbuf,
             const short* __restrict__ Wfg2B, const float* __restrict__ bias,
             const short* __restrict__ capB,
             const short* __restrict__ WkB, const float* __restrict__ bk,
             const float* __restrict__ qg, float* __restrict__ scorep)
{
    __shared__ short lds[2][16384];
    __shared__ float sp[256];
    const int tid = threadIdx.x;
    const int bm = blockIdx.y * 128;
    const int bn = blockIdx.x * 128;
    const int z = blockIdx.z;
    const short* A1 = Gbuf + (size_t)z * 256;
    const short* B2 = WkB + (size_t)z * 256 * 512;

    const int lane = tid & 63;
    const int wr = (tid >> 7) & 1, wc = (tid >> 6) & 1;
    const int fr = lane & 15, kc = lane >> 4;
    const int r0 = tid >> 2;
    const int e0 = (((tid & 3) ^ ((r0 >> 1) & 3))) * 8;
    const int kce = (kc ^ ((fr >> 1) & 3)) * 8;

    auto stage = [&](int ph, int s) {
        short* b = lds[ph];
        const int k0 = s * 32;
        glds16(capB + (size_t)(bm + r0) * 512 + k0 + e0,      b + 8192 + tid * 8);
        glds16(capB + (size_t)(bm + r0 + 64) * 512 + k0 + e0, b + 8192 + (tid + 256) * 8);
        glds16(B2 + (size_t)(bn + r0) * 512 + k0 + e0,        b + 12288 + tid * 8);
        glds16(B2 + (size_t)(bn + r0 + 64) * 512 + k0 + e0,   b + 12288 + (tid + 256) * 8);
        if (s < 8) {
            glds16(A1 + (size_t)(bm + r0) * 512 + k0 + e0,        b + tid * 8);
            glds16(A1 + (size_t)(bm + r0 + 64) * 512 + k0 + e0,   b + (tid + 256) * 8);
            glds16(Wfg2B + (size_t)(bn + r0) * 256 + k0 + e0,     b + 4096 + tid * 8);
            glds16(Wfg2B + (size_t)(bn + r0 + 64) * 256 + k0 + e0, b + 4096 + (tid + 256) * 8);
        }
    };

    f32x4 acc1[4][4], acc2[4][4];
#pragma unroll
    for (int i = 0; i < 4; ++i)
#pragma unroll
        for (int j = 0; j < 4; ++j) {
            acc1[i][j] = (f32x4){0.f, 0.f, 0.f, 0.f};
            acc2[i][j] = (f32x4){0.f, 0.f, 0.f, 0.f};
        }

    stage(0, 0);
    __syncthreads();
    for (int s = 0; s < 16; ++s) {
        if (s + 1 < 16) stage((s + 1) & 1, s + 1);
        const short* b = lds[s & 1];
        bf16x8 ah[4], bh[4];
#pragma unroll
        for (int i = 0; i < 4; ++i)
            ah[i] = *(const bf16x8*)&b[8192 + (wr * 64 + i * 16 + fr) * 32 + kce];
#pragma unroll
        for (int i = 0; i < 4; ++i)
            bh[i] = *(const bf16x8*)&b[12288 + (wc * 64 + i * 16 + fr) * 32 + kce];
#pragma unroll
        for (int mi = 0; mi < 4; ++mi)
#pragma unroll
            for (int ni = 0; ni < 4; ++ni)
                acc2[mi][ni] = __builtin_amdgcn_mfma_f32_16x16x32_bf16(ah[mi], bh[ni], acc2[mi][ni], 0, 0, 0);
        if (s < 8) {
#pragma unroll
            for (int i = 0; i < 4; ++i)
                ah[i] = *(const bf16x8*)&b[(wr * 64 + i * 16 + fr) * 32 + kce];
#pragma unroll
            for (int i = 0; i < 4; ++i)
                bh[i] = *(const bf16x8*)&b[4096 + (wc * 64 + i * 16 + fr) * 32 + kce];
#pragma unroll
            for (int mi = 0; mi < 4; ++mi)
#pragma unroll
                for (int ni = 0; ni < 4; ++ni)
                    acc1[mi][ni] = __builtin_amdgcn_mfma_f32_16x16x32_bf16(ah[mi], bh[ni], acc1[mi][ni], 0, 0, 0);
        }
        __syncthreads();
    }

    float qgv[4];
    float pt[4][4];
    {
        const int b = bm >> 8;
#pragma unroll
        for (int ni = 0; ni < 4; ++ni)
            qgv[ni] = qg[b * 512 + z * 256 + bn + wc * 64 + ni * 16 + fr];
#pragma unroll
        for (int mi = 0; mi < 4; ++mi)
#pragma unroll
            for (int r = 0; r < 4; ++r) pt[mi][r] = 0.f;
    }

#pragma unroll
    for (int mi = 0; mi < 4; ++mi) {
#pragma unroll
        for (int ni = 0; ni < 4; ++ni) {
#pragma unroll
            for (int r = 0; r < 4; ++r) {
                const int col = bn + wc * 64 + ni * 16 + fr;
                const float v = acc1[mi][ni][r] + bias[col];
                const float e = acc2[mi][ni][r] + bk[z * 256 + col];
                const float kgv = e / (1.f + expf(-v));
                pt[mi][r] += kgv * qgv[ni];
            }
        }
    }

#pragma unroll
    for (int mi = 0; mi < 4; ++mi) {
#pragma unroll
        for (int r = 0; r < 4; ++r) {
            float p = pt[mi][r];
            p += __shfl_xor(p, 1);
            p += __shfl_xor(p, 2);
            p += __shfl_xor(p, 4);
            p += __shfl_xor(p, 8);
            if (fr == 0) {
                const int row_local = wr * 64 + mi * 16 + kc * 4 + r;
                sp[row_local * 2 + wc] = p;
            }
        }
    }
    __syncthreads();
    if (tid < 128) {
        const int row = bm + tid;
        const float s = sp[tid * 2] + sp[tid * 2 + 1];
        const int b = row >> 8, j = row & 255;
        scorep[((size_t)(b * 2 + z) * 256 + j) * 2 + blockIdx.x] = s;
    }
}

// ---------------- fused softmax + pbar (LDS) + BN1/residual ----------------
__global__ __launch_bounds__(256)
void pbar_bnx(const float* __restrict__ scorep, const short* __restrict__ capB,
              const float* __restrict__ cap, const int* __restrict__ lengths,
              const float* __restrict__ Wv, const float* __restrict__ bv,
              const float* __restrict__ g1, const float* __restrict__ b1,
              const float* __restrict__ m1, const float* __restrict__ v1,
              float* __restrict__ xga)
{
    __shared__ float sc[512], red[512], pb[1024];
    const int b = blockIdx.x;
    const int t = threadIdx.x;
#pragma unroll
    for (int i = 0; i < 2; ++i) {
        const int o = t + i * 256;
        const int h = o >> 8, j = o & 255;
        const size_t si = ((size_t)(b * 2 + h) * 256 + j) * 2;
        sc[o] = floorf((scorep[si] + scorep[si + 1]) * 0.0625f);
    }
    __syncthreads();
    red[t] = sc[t]; red[t + 256] = sc[t + 256];
    __syncthreads();
    for (int s = 128; s > 0; s >>= 1) {
        if (t < s) {
            red[t] = fmaxf(red[t], red[t + s]);
            red[256 + t] = fmaxf(red[256 + t], red[256 + t + s]);
        }
        __syncthreads();
    }
    const float mx0 = red[0], mx1 = red[256];
    __syncthreads();
    const float e0 = expf(sc[t] - mx0);
    const float e1 = expf(sc[t + 256] - mx1);
    red[t] = e0; red[t + 256] = e1;
    __syncthreads();
    for (int s = 128; s > 0; s >>= 1) {
        if (t < s) { red[t] += red[t + s]; red[256 + t] += red[256 + t + s]; }
        __syncthreads();
    }
    sc[t] = e0 / red[0];
    sc[t + 256] = e1 / red[256];
    __syncthreads();

    float a00 = 0.f, a01 = 0.f, a10 = 0.f, a11 = 0.f;
    for (int j = 0; j < 256; ++j) {
        const float p0 = sc[j], p1 = sc[256 + j];
        const float cv0 = bf2f(capB[((size_t)(b * 256 + j)) * 512 + t]);
        const float cv1 = bf2f(capB[((size_t)(b * 256 + j)) * 512 + 256 + t]);
        a00 += p0 * cv0; a01 += p0 * cv1;
        a10 += p1 * cv0; a11 += p1 * cv1;
    }
    pb[t] = a00; pb[256 + t] = a01;
    pb[512 + t] = a10; pb[768 + t] = a11;
    __syncthreads();

    int r = lengths[b] - 1;
    if (r < 0) r = 0;
    if (r > 255) r = 255;
    const size_t base = ((size_t)b * 256 + r) * 512;
    float x0 = 0.f, x1 = 0.f;
    {
        const float4* w4 = (const float4*)(Wv + (size_t)t * 512);
        for (int k4 = 0; k4 < 128; ++k4) {
            float4 w = w4[k4];
            x0 += w.x * pb[k4 * 4 + 0] + w.y * pb[k4 * 4 + 1]
                + w.z * pb[k4 * 4 + 2] + w.w * pb[k4 * 4 + 3];
        }
        x0 += bv[t];
    }
    {
        const float4* w4 = (const float4*)(Wv + (size_t)(t + 256) * 512);
        for (int k4 = 0; k4 < 128; ++k4) {
            float4 w = w4[k4];
            x1 += w.x * pb[512 + k4 * 4 + 0] + w.y * pb[512 + k4 * 4 + 1]
                + w.z * pb[512 + k4 * 4 + 2] + w.w * pb[512 + k4 * 4 + 3];
        }
        x1 += bv[t + 256];
    }
    const int c0 = t, c1 = t + 256;
    const float s0 = g1[c0] / sqrtf(v1[c0] + 1e-5f);
    const float s1 = g1[c1] / sqrtf(v1[c1] + 1e-5f);
    xga[b * 512 + c0] = cap[base + c0] + (x0 - m1[c0]) * s0 + b1[c0];
    xga[b * 512 + c1] = cap[base + c1] + (x1 - m1[c1]) * s1 + b1[c1];
}

// ---------------- MLP strip GEMMs (weights read once) ----------------
__global__ __launch_bounds__(256)
void mlp1(const float* __restrict__ xga, const float* __restrict__ W,
          const float* __restrict__ bias, float* __restrict__ hid)
{
    __shared__ float xs[16 * 512];
    const int r0 = blockIdx.y * 16;
    const int c0 = blockIdx.x * 64;
    for (int i = threadIdx.x; i < 2048; i += 256)
        ((float4*)xs)[i] = ((const float4*)(xga + (size_t)r0 * 512))[i];
    __syncthreads();
    const int col = c0 + (threadIdx.x & 63);
    const int rg = (threadIdx.x >> 6) * 4;
    float acc[4] = {0.f, 0.f, 0.f, 0.f};
    const float4* w4 = (const float4*)(W + (size_t)col * 512);
    for (int k4 = 0; k4 < 128; ++k4) {
        float4 w = w4[k4];
#pragma unroll
        for (int rr = 0; rr < 4; ++rr) {
            float4 x = *(const float4*)&xs[(rg + rr) * 512 + k4 * 4];
            acc[rr] += w.x * x.x + w.y * x.y + w.z * x.z + w.w * x.w;
        }
    }
    const float bb = bias[col];
#pragma unroll
    for (int rr = 0; rr < 4; ++rr)
        hid[(size_t)(r0 + rg + rr) * 1024 + col] = fmaxf(acc[rr] + bb, 0.f);
}

__global__ __launch_bounds__(256)
void mlp2(const float* __restrict__ hid, const float* __restrict__ W,
          const float* __restrict__ bias, const float* __restrict__ xga,
          float* __restrict__ tex)
{
    __shared__ float xs[16 * 1024];
    const int r0 = blockIdx.y * 16;
    const int c0 = blockIdx.x * 64;
    for (int i = threadIdx.x; i < 4096; i += 256)
        ((float4*)xs)[i] = ((const float4*)(hid + (size_t)r0 * 1024))[i];
    __syncthreads();
    const int col = c0 + (threadIdx.x & 63);
    const int rg = (threadIdx.x >> 6) * 4;
    float acc[4] = {0.f, 0.f, 0.f, 0.f};
    const float4* w4 = (const float4*)(W + (size_t)col * 1024);
    for (int k4 = 0; k4 < 256; ++k4) {
        float4 w = w4[k4];
#pragma unroll
        for (int rr = 0; rr < 4; ++rr) {
            float4 x = *(const float4*)&xs[(rg + rr) * 1024 + k4 * 4];
            acc[rr] += w.x * x.x + w.y * x.y + w.z * x.z + w.w * x.w;
        }
    }
    const float bb = bias[col];
#pragma unroll
    for (int rr = 0; rr < 4; ++rr) {
        const int row = r0 + rg + rr;
        tex[(size_t)row * 512 + col] = acc[rr] + bb + xga[(size_t)row * 512 + col];
    }
}

__global__ __launch_bounds__(256)
void norm_out(const float* __restrict__ tex, float* __restrict__ out)
{
    __shared__ float red[256];
    const int b = blockIdx.x;
    const int t = threadIdx.x;
    const float a = tex[b * 512 + t];
    const float c = tex[b * 512 + 256 + t];
    red[t] = a * a + c * c;
    __syncthreads();
    for (int s = 128; s > 0; s >>= 1) {
        if (t < s) red[t] += red[t + s];
        __syncthreads();
    }
    const float inv = 1.f / (sqrtf(red[0]) + 1e-8f);
    out[b * 512 + t] = a * inv;
    out[b * 512 + 256 + t] = c * inv;
}

extern "C" void kernel_launch(void* const* d_in, const int* in_sizes, int n_in,
                              void* d_out, int out_size, void* d_ws, size_t ws_size,
                              hipStream_t stream)
{
    const float* cap = (const float*)d_in[0];
    const int* lengths = (const int*)d_in[1];
    const float* Wq  = (const float*)d_in[2];
    const float* Wk  = (const float*)d_in[3];
    const float* Wv  = (const float*)d_in[4];
    const float* bq  = (const float*)d_in[5];
    const float* bk  = (const float*)d_in[6];
    const float* bv  = (const float*)d_in[7];
    const float* Wfq = (const float*)d_in[8];
    const float* bfq = (const float*)d_in[9];
    const float* Wfk = (const float*)d_in[10];
    const float* bfk = (const float*)d_in[11];
    const float* Wfg = (const float*)d_in[12];
    const float* bfg = (const float*)d_in[13];
    const float* g1  = (const float*)d_in[14];
    const float* b1  = (const float*)d_in[15];
    const float* m1  = (const float*)d_in[16];
    const float* v1  = (const float*)d_in[17];
    const float* Wm1 = (const float*)d_in[30];
    const float* bm1 = (const float*)d_in[31];
    const float* Wm2 = (const float*)d_in[32];
    const float* bm2 = (const float*)d_in[33];
    float* out = (float*)d_out;

    char* w = (char*)d_ws;
    const size_t MB = 1024 * 1024;
    short* capB = (short*)(w);                 // 32MB bf16 cap
    short* Gbuf = (short*)(w + 32 * MB);       // 32MB [32768,512] bf16
    char* wp = w + 64 * MB;
    short* WkB   = (short*)wp; wp += 524288;
    short* WaB   = (short*)wp; wp += 524288;
    short* WbB   = (short*)wp; wp += 524288;
    short* Wfg2B = (short*)wp; wp += 131072;
    float* ba     = (float*)wp; wp += 2048;
    float* bb     = (float*)wp; wp += 2048;
    float* qg     = (float*)wp; wp += 262144;
    float* scorep = (float*)wp; wp += 524288;   // [128][2][256][2]
    float* xga    = (float*)wp; wp += 262144;
    float* hid    = (float*)wp; wp += 524288;
    float* tex    = (float*)wp; wp += 262144;

    // 1. prep: casts + composed weights
    PrepArgs pa;
    pa.src[0] = cap;          pa.dst[0] = capB;  pa.n4[0] = 4194304;
    pa.src[1] = Wk;           pa.dst[1] = WkB;   pa.n4[1] = 65536;
    pa.src[2] = Wfg + 65536;  pa.dst[2] = Wfg2B; pa.n4[2] = 16384;
    pa.Wq = Wq; pa.bq = bq; pa.Wfq = Wfq; pa.bfq = bfq;
    pa.Wk = Wk; pa.bk = bk; pa.Wfk = Wfk; pa.bfk = bfk;
    pa.WaB = WaB; pa.WbB = WbB; pa.ba = ba; pa.bb = bb;
    prep_kernel<<<dim3(4096, 5), 256, 0, stream>>>(pa);

    // 2. gemm_g (1024 blocks) + qg (256 blocks)
    gemm_g_qg<<<dim3(1280), 256, 0, stream>>>(capB, WaB, WbB, ba, bb, Gbuf,
                                              cap, Wq, bq, Wfg, bfg, lengths, qg);

    // 3. kg gemm (interleaved dual kloop) + in-kernel K (fp32) + fused scores
    gemm_kg<<<dim3(2, 256, 2), 256, 0, stream>>>(Gbuf, Wfg2B, bfg + 256,
                                                 capB, WkB, bk, qg, scorep);

    // 4. softmax + pbar + BN/residual
    pbar_bnx<<<dim3(128), 256, 0, stream>>>(scorep, capB, cap, lengths,
                                            Wv, bv, g1, b1, m1, v1, xga);

    // 5-7. MLP strip GEMMs + norm
    mlp1<<<dim3(16, 8), 256, 0, stream>>>(xga, Wm1, bm1, hid);
    mlp2<<<dim3(8, 8), 256, 0, stream>>>(hid, Wm2, bm2, xga, tex);
    norm_out<<<dim3(128), 256, 0, stream>>>(tex, out);
}

// Round 21
// 265.907 us; speedup vs baseline: 2.5547x; 1.1103x over previous
//
#include <hip/hip_runtime.h>
#include <math.h>

// BS=128, L=256, D=512, H=2, DK=256.
// Conv branches dead (gather idx < 256). ALL GEMMs 1-pass bf16 MFMA, 2-phase
// __syncthreads-only. Compositions: Wa = Wfq@Wq_h, Wb = Wfk@Wk_h (both
// gate-shielded). G = (cap@Wb^T+bb)*(cap@Wa^T+ba). K never stored (fp32 in
// kg epilogue). V GEMM removed via x=(p@cap)@Wv^T+bv.
// 8 dispatches: prep(fused) | gemm_g | qg | gemm_kg | pbar_bnx(fused) |
// mlp1 | mlp2 | norm. r20 lesson: fusing qg into gemm_g raised VGPR 112->160
// and halved occupancy — MFMA kernels stay homogeneous.

typedef short bf16x8 __attribute__((ext_vector_type(8)));
typedef float f32x4 __attribute__((ext_vector_type(4)));
typedef short short4v __attribute__((ext_vector_type(4)));

__device__ __forceinline__ short f2bf(float x) {
    union { float f; unsigned u; } c; c.f = x;
    unsigned r = c.u + 0x7FFFu + ((c.u >> 16) & 1u);
    return (short)(r >> 16);
}
__device__ __forceinline__ float bf2f(short h) {
    union { float f; unsigned u; } c; c.u = ((unsigned)(unsigned short)h) << 16;
    return c.f;
}
__device__ __forceinline__ void glds16(const void* g, void* l) {
    __builtin_amdgcn_global_load_lds(
        (const __attribute__((address_space(1))) void*)g,
        (__attribute__((address_space(3))) void*)l, 16, 0, 0);
}

// ---------------- prep: bf16 casts + composed weights, one dispatch ----------------
struct PrepArgs {
    const float* src[3];
    short* dst[3];
    int n4[3];
    const float *Wq, *bq, *Wfq, *bfq, *Wk, *bk, *Wfk, *bfk;
    short *WaB, *WbB;
    float *ba, *bb;
};
__global__ __launch_bounds__(256) void prep_kernel(PrepArgs a)
{
    const int y = blockIdx.y;
    const int t = threadIdx.x;
    if (y < 3) {
        const float4* s = (const float4*)a.src[y];
        short* d = a.dst[y];
        const int n4 = a.n4[y];
        for (int i = blockIdx.x * 256 + t; i < n4; i += gridDim.x * 256) {
            float4 x = s[i];
            short4v h;
            h.x = f2bf(x.x); h.y = f2bf(x.y); h.z = f2bf(x.z); h.w = f2bf(x.w);
            *(short4v*)&d[i * 4] = h;
        }
        return;
    }
    if (blockIdx.x >= 512) return;
    __shared__ float fq[256];
    __shared__ float redc[256];
    const int op = blockIdx.x;
    const int h = op >> 8, o = op & 255;
    const bool second = (y == 4);
    const float* W  = second ? a.Wk  : a.Wq;
    const float* bv = second ? a.bk  : a.bq;
    const float* F  = second ? a.Wfk : a.Wfq;
    const float* bf = second ? a.bfk : a.bfq;
    short* WB   = second ? a.WbB : a.WaB;
    float* bout = second ? a.bb  : a.ba;

    fq[t] = F[o * 256 + t];
    redc[t] = fq[t] * bv[h * 256 + t];
    __syncthreads();
    for (int s = 128; s > 0; s >>= 1) {
        if (t < s) redc[t] += redc[t + s];
        __syncthreads();
    }
    if (t == 0) bout[op] = redc[0] + bf[o];
    float s0 = 0.f, s1 = 0.f;
    for (int d = 0; d < 256; ++d) {
        const float f = fq[d];
        const float* wr = W + (size_t)(h * 256 + d) * 512;
        s0 += f * wr[t];
        s1 += f * wr[t + 256];
    }
    const size_t ro = (size_t)op * 512;
    WB[ro + t] = f2bf(s0);
    WB[ro + 256 + t] = f2bf(s1);
}

// ---------------- G: dual-B 2-phase, G = (cap@Wb^T+bb)*(cap@Wa^T+ba) ----------------
__global__ __launch_bounds__(256, 2)
void gemm_g(const short* __restrict__ capB,
            const short* __restrict__ WaB, const short* __restrict__ WbB,
            const float* __restrict__ ba, const float* __restrict__ bb,
            short* __restrict__ Gbuf)
{
    __shared__ short lds[2][12288];   // A 8KB | B1 8KB | B2 8KB per phase
    const int tid = threadIdx.x;
    const int bm = blockIdx.y * 128;
    const int bn = blockIdx.x * 128;   // within-head col block
    const int z = blockIdx.z;
    const short* B1 = WaB + (size_t)z * 256 * 512;
    const short* B2 = WbB + (size_t)z * 256 * 512;

    const int lane = tid & 63;
    const int wr = (tid >> 7) & 1, wc = (tid >> 6) & 1;
    const int fr = lane & 15, kc = lane >> 4;
    const int r0 = tid >> 2;
    const int e0 = (((tid & 3) ^ ((r0 >> 1) & 3))) * 8;
    const int kce = (kc ^ ((fr >> 1) & 3)) * 8;

    auto stage = [&](int ph, int k0) {
        short* b = lds[ph];
        glds16(capB + (size_t)(bm + r0) * 512 + k0 + e0,      b + tid * 8);
        glds16(capB + (size_t)(bm + r0 + 64) * 512 + k0 + e0, b + (tid + 256) * 8);
        glds16(B1 + (size_t)(bn + r0) * 512 + k0 + e0,        b + 4096 + tid * 8);
        glds16(B1 + (size_t)(bn + r0 + 64) * 512 + k0 + e0,   b + 4096 + (tid + 256) * 8);
        glds16(B2 + (size_t)(bn + r0) * 512 + k0 + e0,        b + 8192 + tid * 8);
        glds16(B2 + (size_t)(bn + r0 + 64) * 512 + k0 + e0,   b + 8192 + (tid + 256) * 8);
    };

    f32x4 acc1[4][4], acc2[4][4];
#pragma unroll
    for (int i = 0; i < 4; ++i)
#pragma unroll
        for (int j = 0; j < 4; ++j) {
            acc1[i][j] = (f32x4){0.f, 0.f, 0.f, 0.f};
            acc2[i][j] = (f32x4){0.f, 0.f, 0.f, 0.f};
        }

    stage(0, 0);
    __syncthreads();
    for (int s = 0; s < 16; ++s) {
        if (s + 1 < 16) stage((s + 1) & 1, (s + 1) * 32);
        const short* b = lds[s & 1];
        bf16x8 ah[4], bh[4];
#pragma unroll
        for (int i = 0; i < 4; ++i)
            ah[i] = *(const bf16x8*)&b[(wr * 64 + i * 16 + fr) * 32 + kce];
#pragma unroll
        for (int i = 0; i < 4; ++i)
            bh[i] = *(const bf16x8*)&b[4096 + (wc * 64 + i * 16 + fr) * 32 + kce];
#pragma unroll
        for (int mi = 0; mi < 4; ++mi)
#pragma unroll
            for (int ni = 0; ni < 4; ++ni)
                acc1[mi][ni] = __builtin_amdgcn_mfma_f32_16x16x32_bf16(ah[mi], bh[ni], acc1[mi][ni], 0, 0, 0);
#pragma unroll
        for (int i = 0; i < 4; ++i)
            bh[i] = *(const bf16x8*)&b[8192 + (wc * 64 + i * 16 + fr) * 32 + kce];
#pragma unroll
        for (int mi = 0; mi < 4; ++mi)
#pragma unroll
            for (int ni = 0; ni < 4; ++ni)
                acc2[mi][ni] = __builtin_amdgcn_mfma_f32_16x16x32_bf16(ah[mi], bh[ni], acc2[mi][ni], 0, 0, 0);
        __syncthreads();
    }

#pragma unroll
    for (int mi = 0; mi < 4; ++mi) {
#pragma unroll
        for (int ni = 0; ni < 4; ++ni) {
#pragma unroll
            for (int r = 0; r < 4; ++r) {
                const int row = bm + wr * 64 + mi * 16 + kc * 4 + r;
                const int col = bn + wc * 64 + ni * 16 + fr;
                const float av  = acc1[mi][ni][r] + ba[z * 256 + col];
                const float lin = acc2[mi][ni][r] + bb[z * 256 + col];
                Gbuf[(size_t)row * 512 + z * 256 + col] = f2bf(lin * av);
            }
        }
    }
}

// ---------------- qg at gathered rows: Q fp32-exact from cap ----------------
__global__ __launch_bounds__(256)
void qg_kernel(const float* __restrict__ cap,
               const short* __restrict__ Gbuf,
               const float* __restrict__ Wq, const float* __restrict__ bq,
               const float* __restrict__ Wfg, const float* __restrict__ bfg,
               const int* __restrict__ lengths, float* __restrict__ qg)
{
    __shared__ float cr[512];
    __shared__ float gs[256];
    const int b = blockIdx.x >> 1, h = blockIdx.x & 1;
    const int t = threadIdx.x;
    int r = lengths[b] - 1;
    if (r < 0) r = 0;
    if (r > 255) r = 255;
    const size_t base = ((size_t)b * 256 + r) * 512;
    cr[t] = cap[base + t];
    cr[t + 256] = cap[base + 256 + t];
    gs[t] = bf2f(Gbuf[base + h * 256 + t]);
    __syncthreads();
    const float4* wq4 = (const float4*)(Wq + (size_t)(h * 256 + t) * 512);
    float q = 0.f;
    for (int k4 = 0; k4 < 128; ++k4) {
        float4 w = wq4[k4];
        q += w.x * cr[k4 * 4 + 0] + w.y * cr[k4 * 4 + 1]
           + w.z * cr[k4 * 4 + 2] + w.w * cr[k4 * 4 + 3];
    }
    q += bq[h * 256 + t];
    const float4* w4 = (const float4*)(Wfg + (size_t)t * 256);
    float a = 0.f;
    for (int k4 = 0; k4 < 64; ++k4) {
        float4 w = w4[k4];
        a += w.x * gs[k4 * 4 + 0] + w.y * gs[k4 * 4 + 1]
           + w.z * gs[k4 * 4 + 2] + w.w * gs[k4 * 4 + 3];
    }
    a += bfg[t];
    qg[b * 512 + h * 256 + t] = q / (1.f + expf(-a));
}

// ---------------- kg: interleaved dual kloop + fused score partials ----------------
__global__ __launch_bounds__(256, 2)
void gemm_kg(const short* __restrict__ Gbuf,
             const short* __restrict__ Wfg2B, const float* __restrict__ bias,
             const short* __restrict__ capB,
             const short* __restrict__ WkB, const float* __restrict__ bk,
             const float* __restrict__ qg, float* __restrict__ scorep)
{
    __shared__ short lds[2][16384];
    __shared__ float sp[256];
    const int tid = threadIdx.x;
    const int bm = blockIdx.y * 128;
    const int bn = blockIdx.x * 128;
    const int z = blockIdx.z;
    const short* A1 = Gbuf + (size_t)z * 256;
    const short* B2 = WkB + (size_t)z * 256 * 512;

    const int lane = tid & 63;
    const int wr = (tid >> 7) & 1, wc = (tid >> 6) & 1;
    const int fr = lane & 15, kc = lane >> 4;
    const int r0 = tid >> 2;
    const int e0 = (((tid & 3) ^ ((r0 >> 1) & 3))) * 8;
    const int kce = (kc ^ ((fr >> 1) & 3)) * 8;

    auto stage = [&](int ph, int s) {
        short* b = lds[ph];
        const int k0 = s * 32;
        glds16(capB + (size_t)(bm + r0) * 512 + k0 + e0,      b + 8192 + tid * 8);
        glds16(capB + (size_t)(bm + r0 + 64) * 512 + k0 + e0, b + 8192 + (tid + 256) * 8);
        glds16(B2 + (size_t)(bn + r0) * 512 + k0 + e0,        b + 12288 + tid * 8);
        glds16(B2 + (size_t)(bn + r0 + 64) * 512 + k0 + e0,   b + 12288 + (tid + 256) * 8);
        if (s < 8) {
            glds16(A1 + (size_t)(bm + r0) * 512 + k0 + e0,        b + tid * 8);
            glds16(A1 + (size_t)(bm + r0 + 64) * 512 + k0 + e0,   b + (tid + 256) * 8);
            glds16(Wfg2B + (size_t)(bn + r0) * 256 + k0 + e0,     b + 4096 + tid * 8);
            glds16(Wfg2B + (size_t)(bn + r0 + 64) * 256 + k0 + e0, b + 4096 + (tid + 256) * 8);
        }
    };

    f32x4 acc1[4][4], acc2[4][4];
#pragma unroll
    for (int i = 0; i < 4; ++i)
#pragma unroll
        for (int j = 0; j < 4; ++j) {
            acc1[i][j] = (f32x4){0.f, 0.f, 0.f, 0.f};
            acc2[i][j] = (f32x4){0.f, 0.f, 0.f, 0.f};
        }

    stage(0, 0);
    __syncthreads();
    for (int s = 0; s < 16; ++s) {
        if (s + 1 < 16) stage((s + 1) & 1, s + 1);
        const short* b = lds[s & 1];
        bf16x8 ah[4], bh[4];
#pragma unroll
        for (int i = 0; i < 4; ++i)
            ah[i] = *(const bf16x8*)&b[8192 + (wr * 64 + i * 16 + fr) * 32 + kce];
#pragma unroll
        for (int i = 0; i < 4; ++i)
            bh[i] = *(const bf16x8*)&b[12288 + (wc * 64 + i * 16 + fr) * 32 + kce];
#pragma unroll
        for (int mi = 0; mi < 4; ++mi)
#pragma unroll
            for (int ni = 0; ni < 4; ++ni)
                acc2[mi][ni] = __builtin_amdgcn_mfma_f32_16x16x32_bf16(ah[mi], bh[ni], acc2[mi][ni], 0, 0, 0);
        if (s < 8) {
#pragma unroll
            for (int i = 0; i < 4; ++i)
                ah[i] = *(const bf16x8*)&b[(wr * 64 + i * 16 + fr) * 32 + kce];
#pragma unroll
            for (int i = 0; i < 4; ++i)
                bh[i] = *(const bf16x8*)&b[4096 + (wc * 64 + i * 16 + fr) * 32 + kce];
#pragma unroll
            for (int mi = 0; mi < 4; ++mi)
#pragma unroll
                for (int ni = 0; ni < 4; ++ni)
                    acc1[mi][ni] = __builtin_amdgcn_mfma_f32_16x16x32_bf16(ah[mi], bh[ni], acc1[mi][ni], 0, 0, 0);
        }
        __syncthreads();
    }

    float qgv[4];
    float pt[4][4];
    {
        const int b = bm >> 8;
#pragma unroll
        for (int ni = 0; ni < 4; ++ni)
            qgv[ni] = qg[b * 512 + z * 256 + bn + wc * 64 + ni * 16 + fr];
#pragma unroll
        for (int mi = 0; mi < 4; ++mi)
#pragma unroll
            for (int r = 0; r < 4; ++r) pt[mi][r] = 0.f;
    }

#pragma unroll
    for (int mi = 0; mi < 4; ++mi) {
#pragma unroll
        for (int ni = 0; ni < 4; ++ni) {
#pragma unroll
            for (int r = 0; r < 4; ++r) {
                const int col = bn + wc * 64 + ni * 16 + fr;
                const float v = acc1[mi][ni][r] + bias[col];
                const float e = acc2[mi][ni][r] + bk[z * 256 + col];
                const float kgv = e / (1.f + expf(-v));
                pt[mi][r] += kgv * qgv[ni];
            }
        }
    }

#pragma unroll
    for (int mi = 0; mi < 4; ++mi) {
#pragma unroll
        for (int r = 0; r < 4; ++r) {
            float p = pt[mi][r];
            p += __shfl_xor(p, 1);
            p += __shfl_xor(p, 2);
            p += __shfl_xor(p, 4);
            p += __shfl_xor(p, 8);
            if (fr == 0) {
                const int row_local = wr * 64 + mi * 16 + kc * 4 + r;
                sp[row_local * 2 + wc] = p;
            }
        }
    }
    __syncthreads();
    if (tid < 128) {
        const int row = bm + tid;
        const float s = sp[tid * 2] + sp[tid * 2 + 1];
        const int b = row >> 8, j = row & 255;
        scorep[((size_t)(b * 2 + z) * 256 + j) * 2 + blockIdx.x] = s;
    }
}

// ---------------- fused softmax + pbar (LDS) + BN1/residual ----------------
__global__ __launch_bounds__(256)
void pbar_bnx(const float* __restrict__ scorep, const short* __restrict__ capB,
              const float* __restrict__ cap, const int* __restrict__ lengths,
              const float* __restrict__ Wv, const float* __restrict__ bv,
              const float* __restrict__ g1, const float* __restrict__ b1,
              const float* __restrict__ m1, const float* __restrict__ v1,
              float* __restrict__ xga)
{
    __shared__ float sc[512], red[512], pb[1024];
    const int b = blockIdx.x;
    const int t = threadIdx.x;
#pragma unroll
    for (int i = 0; i < 2; ++i) {
        const int o = t + i * 256;
        const int h = o >> 8, j = o & 255;
        const size_t si = ((size_t)(b * 2 + h) * 256 + j) * 2;
        sc[o] = floorf((scorep[si] + scorep[si + 1]) * 0.0625f);
    }
    __syncthreads();
    red[t] = sc[t]; red[t + 256] = sc[t + 256];
    __syncthreads();
    for (int s = 128; s > 0; s >>= 1) {
        if (t < s) {
            red[t] = fmaxf(red[t], red[t + s]);
            red[256 + t] = fmaxf(red[256 + t], red[256 + t + s]);
        }
        __syncthreads();
    }
    const float mx0 = red[0], mx1 = red[256];
    __syncthreads();
    const float e0 = expf(sc[t] - mx0);
    const float e1 = expf(sc[t + 256] - mx1);
    red[t] = e0; red[t + 256] = e1;
    __syncthreads();
    for (int s = 128; s > 0; s >>= 1) {
        if (t < s) { red[t] += red[t + s]; red[256 + t] += red[256 + t + s]; }
        __syncthreads();
    }
    sc[t] = e0 / red[0];
    sc[t + 256] = e1 / red[256];
    __syncthreads();

    float a00 = 0.f, a01 = 0.f, a10 = 0.f, a11 = 0.f;
    for (int j = 0; j < 256; ++j) {
        const float p0 = sc[j], p1 = sc[256 + j];
        const float cv0 = bf2f(capB[((size_t)(b * 256 + j)) * 512 + t]);
        const float cv1 = bf2f(capB[((size_t)(b * 256 + j)) * 512 + 256 + t]);
        a00 += p0 * cv0; a01 += p0 * cv1;
        a10 += p1 * cv0; a11 += p1 * cv1;
    }
    pb[t] = a00; pb[256 + t] = a01;
    pb[512 + t] = a10; pb[768 + t] = a11;
    __syncthreads();

    int r = lengths[b] - 1;
    if (r < 0) r = 0;
    if (r > 255) r = 255;
    const size_t base = ((size_t)b * 256 + r) * 512;
    float x0 = 0.f, x1 = 0.f;
    {
        const float4* w4 = (const float4*)(Wv + (size_t)t * 512);
        for (int k4 = 0; k4 < 128; ++k4) {
            float4 w = w4[k4];
            x0 += w.x * pb[k4 * 4 + 0] + w.y * pb[k4 * 4 + 1]
                + w.z * pb[k4 * 4 + 2] + w.w * pb[k4 * 4 + 3];
        }
        x0 += bv[t];
    }
    {
        const float4* w4 = (const float4*)(Wv + (size_t)(t + 256) * 512);
        for (int k4 = 0; k4 < 128; ++k4) {
            float4 w = w4[k4];
            x1 += w.x * pb[512 + k4 * 4 + 0] + w.y * pb[512 + k4 * 4 + 1]
                + w.z * pb[512 + k4 * 4 + 2] + w.w * pb[512 + k4 * 4 + 3];
        }
        x1 += bv[t + 256];
    }
    const int c0 = t, c1 = t + 256;
    const float s0 = g1[c0] / sqrtf(v1[c0] + 1e-5f);
    const float s1 = g1[c1] / sqrtf(v1[c1] + 1e-5f);
    xga[b * 512 + c0] = cap[base + c0] + (x0 - m1[c0]) * s0 + b1[c0];
    xga[b * 512 + c1] = cap[base + c1] + (x1 - m1[c1]) * s1 + b1[c1];
}

// ---------------- MLP strip GEMMs (weights read once) ----------------
__global__ __launch_bounds__(256)
void mlp1(const float* __restrict__ xga, const float* __restrict__ W,
          const float* __restrict__ bias, float* __restrict__ hid)
{
    __shared__ float xs[16 * 512];
    const int r0 = blockIdx.y * 16;
    const int c0 = blockIdx.x * 64;
    for (int i = threadIdx.x; i < 2048; i += 256)
        ((float4*)xs)[i] = ((const float4*)(xga + (size_t)r0 * 512))[i];
    __syncthreads();
    const int col = c0 + (threadIdx.x & 63);
    const int rg = (threadIdx.x >> 6) * 4;
    float acc[4] = {0.f, 0.f, 0.f, 0.f};
    const float4* w4 = (const float4*)(W + (size_t)col * 512);
    for (int k4 = 0; k4 < 128; ++k4) {
        float4 w = w4[k4];
#pragma unroll
        for (int rr = 0; rr < 4; ++rr) {
            float4 x = *(const float4*)&xs[(rg + rr) * 512 + k4 * 4];
            acc[rr] += w.x * x.x + w.y * x.y + w.z * x.z + w.w * x.w;
        }
    }
    const float bb = bias[col];
#pragma unroll
    for (int rr = 0; rr < 4; ++rr)
        hid[(size_t)(r0 + rg + rr) * 1024 + col] = fmaxf(acc[rr] + bb, 0.f);
}

__global__ __launch_bounds__(256)
void mlp2(const float* __restrict__ hid, const float* __restrict__ W,
          const float* __restrict__ bias, const float* __restrict__ xga,
          float* __restrict__ tex)
{
    __shared__ float xs[16 * 1024];
    const int r0 = blockIdx.y * 16;
    const int c0 = blockIdx.x * 64;
    for (int i = threadIdx.x; i < 4096; i += 256)
        ((float4*)xs)[i] = ((const float4*)(hid + (size_t)r0 * 1024))[i];
    __syncthreads();
    const int col = c0 + (threadIdx.x & 63);
    const int rg = (threadIdx.x >> 6) * 4;
    float acc[4] = {0.f, 0.f, 0.f, 0.f};
    const float4* w4 = (const float4*)(W + (size_t)col * 1024);
    for (int k4 = 0; k4 < 256; ++k4) {
        float4 w = w4[k4];
#pragma unroll
        for (int rr = 0; rr < 4; ++rr) {
            float4 x = *(const float4*)&xs[(rg + rr) * 1024 + k4 * 4];
            acc[rr] += w.x * x.x + w.y * x.y + w.z * x.z + w.w * x.w;
        }
    }
    const float bb = bias[col];
#pragma unroll
    for (int rr = 0; rr < 4; ++rr) {
        const int row = r0 + rg + rr;
        tex[(size_t)row * 512 + col] = acc[rr] + bb + xga[(size_t)row * 512 + col];
    }
}

__global__ __launch_bounds__(256)
void norm_out(const float* __restrict__ tex, float* __restrict__ out)
{
    __shared__ float red[256];
    const int b = blockIdx.x;
    const int t = threadIdx.x;
    const float a = tex[b * 512 + t];
    const float c = tex[b * 512 + 256 + t];
    red[t] = a * a + c * c;
    __syncthreads();
    for (int s = 128; s > 0; s >>= 1) {
        if (t < s) red[t] += red[t + s];
        __syncthreads();
    }
    const float inv = 1.f / (sqrtf(red[0]) + 1e-8f);
    out[b * 512 + t] = a * inv;
    out[b * 512 + 256 + t] = c * inv;
}

extern "C" void kernel_launch(void* const* d_in, const int* in_sizes, int n_in,
                              void* d_out, int out_size, void* d_ws, size_t ws_size,
                              hipStream_t stream)
{
    const float* cap = (const float*)d_in[0];
    const int* lengths = (const int*)d_in[1];
    const float* Wq  = (const float*)d_in[2];
    const float* Wk  = (const float*)d_in[3];
    const float* Wv  = (const float*)d_in[4];
    const float* bq  = (const float*)d_in[5];
    const float* bk  = (const float*)d_in[6];
    const float* bv  = (const float*)d_in[7];
    const float* Wfq = (const float*)d_in[8];
    const float* bfq = (const float*)d_in[9];
    const float* Wfk = (const float*)d_in[10];
    const float* bfk = (const float*)d_in[11];
    const float* Wfg = (const float*)d_in[12];
    const float* bfg = (const float*)d_in[13];
    const float* g1  = (const float*)d_in[14];
    const float* b1  = (const float*)d_in[15];
    const float* m1  = (const float*)d_in[16];
    const float* v1  = (const float*)d_in[17];
    const float* Wm1 = (const float*)d_in[30];
    const float* bm1 = (const float*)d_in[31];
    const float* Wm2 = (const float*)d_in[32];
    const float* bm2 = (const float*)d_in[33];
    float* out = (float*)d_out;

    char* w = (char*)d_ws;
    const size_t MB = 1024 * 1024;
    short* capB = (short*)(w);                 // 32MB bf16 cap
    short* Gbuf = (short*)(w + 32 * MB);       // 32MB [32768,512] bf16
    char* wp = w + 64 * MB;
    short* WkB   = (short*)wp; wp += 524288;
    short* WaB   = (short*)wp; wp += 524288;
    short* WbB   = (short*)wp; wp += 524288;
    short* Wfg2B = (short*)wp; wp += 131072;
    float* ba     = (float*)wp; wp += 2048;
    float* bb     = (float*)wp; wp += 2048;
    float* qg     = (float*)wp; wp += 262144;
    float* scorep = (float*)wp; wp += 524288;   // [128][2][256][2]
    float* xga    = (float*)wp; wp += 262144;
    float* hid    = (float*)wp; wp += 524288;
    float* tex    = (float*)wp; wp += 262144;

    // 1. prep: casts + composed weights (fused)
    PrepArgs pa;
    pa.src[0] = cap;          pa.dst[0] = capB;  pa.n4[0] = 4194304;
    pa.src[1] = Wk;           pa.dst[1] = WkB;   pa.n4[1] = 65536;
    pa.src[2] = Wfg + 65536;  pa.dst[2] = Wfg2B; pa.n4[2] = 16384;
    pa.Wq = Wq; pa.bq = bq; pa.Wfq = Wfq; pa.bfq = bfq;
    pa.Wk = Wk; pa.bk = bk; pa.Wfk = Wfk; pa.bfk = bfk;
    pa.WaB = WaB; pa.WbB = WbB; pa.ba = ba; pa.bb = bb;
    prep_kernel<<<dim3(4096, 5), 256, 0, stream>>>(pa);

    // 2. G = (cap@Wb^T+bb)*(cap@Wa^T+ba)  (dual-B, homogeneous) -> Gbuf
    gemm_g<<<dim3(2, 256, 2), 256, 0, stream>>>(capB, WaB, WbB, ba, bb, Gbuf);

    // 3. qg at gathered rows
    qg_kernel<<<dim3(256), 256, 0, stream>>>(cap, Gbuf, Wq, bq, Wfg, bfg, lengths, qg);

    // 4. kg gemm (interleaved dual kloop) + in-kernel K (fp32) + fused scores
    gemm_kg<<<dim3(2, 256, 2), 256, 0, stream>>>(Gbuf, Wfg2B, bfg + 256,
                                                 capB, WkB, bk, qg, scorep);

    // 5. softmax + pbar + BN/residual (fused)
    pbar_bnx<<<dim3(128), 256, 0, stream>>>(scorep, capB, cap, lengths,
                                            Wv, bv, g1, b1, m1, v1, xga);

    // 6-8. MLP strip GEMMs + norm
    mlp1<<<dim3(16, 8), 256, 0, stream>>>(xga, Wm1, bm1, hid);
    mlp2<<<dim3(8, 8), 256, 0, stream>>>(hid, Wm2, bm2, xga, tex);
    norm_out<<<dim3(128), 256, 0, stream>>>(tex, out);
}